// Round 1
// baseline (137.694 us; speedup 1.0000x reference)
//
#include <hip/hip_runtime.h>
#include <hip/hip_bf16.h>
#include <math.h>

#define N_ROWS 8192
#define DIM    512
#define BM     128
#define BK     32
#define LDK    40   // padded LDS leading dim (f16): stride 20 dwords -> worst 2-way (free)
#define NB     (N_ROWS / BM)   // 64

typedef _Float16 half8 __attribute__((ext_vector_type(8)));
typedef _Float16 half4 __attribute__((ext_vector_type(4)));
typedef float    floatx4 __attribute__((ext_vector_type(4)));

// ---------------- Kernel 1: row L2-normalize fp32 -> f16 ----------------
__global__ __launch_bounds__(128) void normalize_kernel(
    const float* __restrict__ emb, _Float16* __restrict__ out)
{
    const int row = blockIdx.x;
    const int t   = threadIdx.x;

    const float4* rp = (const float4*)(emb + (size_t)row * DIM);
    float4 v = rp[t];                      // 128 thr * 4 = 512
    float ss = v.x*v.x + v.y*v.y + v.z*v.z + v.w*v.w;

    #pragma unroll
    for (int off = 32; off > 0; off >>= 1) ss += __shfl_down(ss, off);

    __shared__ float sred[2];
    if ((t & 63) == 0) sred[t >> 6] = ss;
    __syncthreads();
    const float tot = sred[0] + sred[1];
    const float rn  = 1.0f / fmaxf(sqrtf(tot), 1e-12f);

    half4 h;
    h.x = (_Float16)(v.x * rn);
    h.y = (_Float16)(v.y * rn);
    h.z = (_Float16)(v.z * rn);
    h.w = (_Float16)(v.w * rn);
    ((half4*)(out + (size_t)row * DIM))[t] = h;
}

// ---------------- Kernel 2: fused E*E^T tile + contrastive loss ----------------
__global__ __launch_bounds__(256) void gemmloss_kernel(
    const _Float16* __restrict__ E, const int* __restrict__ labels,
    float* __restrict__ out)
{
    __shared__ __align__(16) _Float16 As[BM * LDK];
    __shared__ __align__(16) _Float16 Bs[BM * LDK];
    __shared__ int   rlab[BM];
    __shared__ int   clab[BM];
    __shared__ float wsum[4];

    // ---- decode triangular block id (br <= bc) ----
    const int bid = blockIdx.x;
    int br = (int)((2.0f * NB + 1.0f -
                    sqrtf((float)((2*NB+1)*(2*NB+1) - 8*bid))) * 0.5f);
    // start(r) = r*NB - r*(r-1)/2
    #define TRI_START(r) ((r)*NB - ((r)*((r)-1))/2)
    while (br > 0 && TRI_START(br) > bid) --br;
    while (TRI_START(br + 1) <= bid) ++br;
    const int bc = br + (bid - TRI_START(br));
    #undef TRI_START

    const int row0 = br * BM;
    const int col0 = bc * BM;

    const int t = threadIdx.x;

    // stage labels (int32 per harness convention)
    if (t < BM) rlab[t]       = labels[row0 + t];
    else        clab[t - BM]  = labels[col0 + (t - BM)];

    const int wave = t >> 6;
    const int lane = t & 63;
    const int wr   = wave >> 1;   // wave row (0..1)
    const int wc   = wave & 1;    // wave col (0..1)
    const int quad = lane >> 4;   // 0..3
    const int l16  = lane & 15;   // 0..15

    floatx4 acc[4][4] = {};

    // staging: 256 thr * 8 f16 = 2048 per pass; tile = 128x32 = 4096 -> 2 passes
    const int srow = t >> 2;          // 0..63
    const int scol = (t & 3) * 8;     // 0,8,16,24

    for (int kk = 0; kk < DIM; kk += BK) {
        __syncthreads();
        #pragma unroll
        for (int p = 0; p < 2; ++p) {
            const int r = srow + p * 64;
            *(uint4*)&As[r * LDK + scol] =
                *(const uint4*)&E[(size_t)(row0 + r) * DIM + kk + scol];
            *(uint4*)&Bs[r * LDK + scol] =
                *(const uint4*)&E[(size_t)(col0 + r) * DIM + kk + scol];
        }
        __syncthreads();

        half8 af[4], bf[4];
        #pragma unroll
        for (int mi = 0; mi < 4; ++mi)
            af[mi] = *(const half8*)&As[(wr*64 + mi*16 + l16) * LDK + quad*8];
        #pragma unroll
        for (int ni = 0; ni < 4; ++ni)
            bf[ni] = *(const half8*)&Bs[(wc*64 + ni*16 + l16) * LDK + quad*8];

        #pragma unroll
        for (int mi = 0; mi < 4; ++mi)
            #pragma unroll
            for (int ni = 0; ni < 4; ++ni)
                acc[mi][ni] = __builtin_amdgcn_mfma_f32_16x16x32_f16(
                    af[mi], bf[ni], acc[mi][ni], 0, 0, 0);
    }

    // ---- epilogue: loss on the 64x64 wave subtile ----
    // C/D layout: col = lane&15, row = quad*4 + reg  [m89-verified]
    float lsum = 0.0f;
    #pragma unroll
    for (int mi = 0; mi < 4; ++mi) {
        const int tr_base = wr*64 + mi*16 + quad*4;   // tile-row base
        #pragma unroll
        for (int ni = 0; ni < 4; ++ni) {
            const int tc = wc*64 + ni*16 + l16;       // tile-col
            const int gj = col0 + tc;
            const int lc = clab[tc];
            #pragma unroll
            for (int reg = 0; reg < 4; ++reg) {
                const int tr = tr_base + reg;
                const int gi = row0 + tr;
                const float s = acc[mi][ni][reg];
                if (gi != gj) {
                    if (rlab[tr] == lc) {
                        const float u = 1.0f - s;
                        lsum += u * u;
                    } else {
                        const float u = s - 0.5f;
                        if (u > 0.0f) lsum += u * u;
                    }
                }
            }
        }
    }

    // off-diagonal blocks counted twice by symmetry
    lsum *= (br == bc) ? 1.0f : 2.0f;

    #pragma unroll
    for (int off = 32; off > 0; off >>= 1) lsum += __shfl_down(lsum, off);
    if (lane == 0) wsum[wave] = lsum;
    __syncthreads();
    if (t == 0) {
        const float tot = wsum[0] + wsum[1] + wsum[2] + wsum[3];
        // N*(N-1) = 8192*8191 = 67100672, exactly representable in fp32
        atomicAdd(out, tot * (1.0f / 67100672.0f));
    }
}

// ---------------- launch ----------------
extern "C" void kernel_launch(void* const* d_in, const int* in_sizes, int n_in,
                              void* d_out, int out_size, void* d_ws, size_t ws_size,
                              hipStream_t stream)
{
    (void)in_sizes; (void)n_in; (void)out_size; (void)ws_size;

    const float* emb    = (const float*)d_in[0];
    const int*   labels = (const int*)d_in[1];
    float*       out    = (float*)d_out;
    _Float16*    En     = (_Float16*)d_ws;   // 8192*512*2 = 8 MB

    hipMemsetAsync(d_out, 0, sizeof(float), stream);
    normalize_kernel<<<N_ROWS, 128, 0, stream>>>(emb, En);

    const int nblocks = NB * (NB + 1) / 2;   // 2080
    gemmloss_kernel<<<nblocks, 256, 0, stream>>>(En, labels, out);
}

// Round 2
// 129.469 us; speedup vs baseline: 1.0635x; 1.0635x over previous
//
#include <hip/hip_runtime.h>
#include <hip/hip_bf16.h>
#include <math.h>

#define N_ROWS 8192
#define DIM    512
#define BM     128
#define BK     32            // K-slice per iter; row-slice = 32 f16 = 64 B = 4 x 16B chunks
#define NB     (N_ROWS / BM) // 64

typedef _Float16 half8 __attribute__((ext_vector_type(8)));
typedef _Float16 half4 __attribute__((ext_vector_type(4)));
typedef float    floatx4 __attribute__((ext_vector_type(4)));

// ---------------- async global->LDS, 16B per lane ----------------
// LDS dest = wave-uniform base + lane*16 (m104/m108). No padding possible;
// layout control is done on the GLOBAL address side (XOR chunk swizzle).
__device__ __forceinline__ void load16_to_lds(const _Float16* g, _Float16* l) {
    __builtin_amdgcn_global_load_lds(
        (const __attribute__((address_space(1))) unsigned int*)g,
        (__attribute__((address_space(3))) unsigned int*)l,
        16, 0, 0);
}

// ---------------- Kernel 1: row L2-normalize fp32 -> f16 (+ zero d_out) ----
__global__ __launch_bounds__(128) void normalize_kernel(
    const float* __restrict__ emb, _Float16* __restrict__ out, float* __restrict__ loss_out)
{
    const int row = blockIdx.x;
    const int t   = threadIdx.x;
    if (row == 0 && t == 0) loss_out[0] = 0.0f;   // replaces hipMemsetAsync dispatch

    const float4* rp = (const float4*)(emb + (size_t)row * DIM);
    float4 v = rp[t];                      // 128 thr * 4 = 512
    float ss = v.x*v.x + v.y*v.y + v.z*v.z + v.w*v.w;

    #pragma unroll
    for (int off = 32; off > 0; off >>= 1) ss += __shfl_down(ss, off);

    __shared__ float sred[2];
    if ((t & 63) == 0) sred[t >> 6] = ss;
    __syncthreads();
    const float tot = sred[0] + sred[1];
    const float rn  = 1.0f / fmaxf(sqrtf(tot), 1e-12f);

    half4 h;
    h.x = (_Float16)(v.x * rn);
    h.y = (_Float16)(v.y * rn);
    h.z = (_Float16)(v.z * rn);
    h.w = (_Float16)(v.w * rn);
    ((half4*)(out + (size_t)row * DIM))[t] = h;
}

// ---------------- Kernel 2: fused E*E^T tile + contrastive loss ----------------
// LDS tile: 128 rows x 32 f16 (64 B), unpadded. Chunk swizzle: 16B chunk c of
// row r stored at slot p = c ^ ((r>>1)&3). Fragment ds_read then hits banks
// exactly 2-way (free). Staging DMA realizes the swizzle via per-lane global
// address c = (lane&3) ^ ((lane>>3)&3)  [since (r>>1)&3 == (lane>>3)&3 here].
__global__ __launch_bounds__(256) void gemmloss_kernel(
    const _Float16* __restrict__ E, const int* __restrict__ labels,
    float* __restrict__ out)
{
    __shared__ __align__(16) _Float16 As[BM * BK];   // 8 KB
    __shared__ __align__(16) _Float16 Bs[BM * BK];   // 8 KB
    __shared__ int   rlab[BM];
    __shared__ int   clab[BM];
    __shared__ float wsum[4];

    // ---- decode triangular block id (br <= bc) ----
    const int bid = blockIdx.x;
    int br = (int)((2.0f * NB + 1.0f -
                    sqrtf((float)((2*NB+1)*(2*NB+1) - 8*bid))) * 0.5f);
    #define TRI_START(r) ((r)*NB - ((r)*((r)-1))/2)
    while (br > 0 && TRI_START(br) > bid) --br;
    while (TRI_START(br + 1) <= bid) ++br;
    const int bc = br + (bid - TRI_START(br));
    #undef TRI_START

    const int row0 = br * BM;
    const int col0 = bc * BM;

    const int t = threadIdx.x;
    if (t < BM) rlab[t]       = labels[row0 + t];
    else        clab[t - BM]  = labels[col0 + (t - BM)];

    const int wave = t >> 6;
    const int lane = t & 63;
    const int wr   = wave >> 1;   // wave row (0..1)
    const int wc   = wave & 1;    // wave col (0..1)
    const int quad = lane >> 4;   // 0..3
    const int l16  = lane & 15;   // 0..15

    // ---- staging pointers: wave w stages rows [32w, 32w+32) of A and B ----
    // segment = 16 rows = 1024 B = one global_load_lds per wave
    const int c       = (lane & 3) ^ ((lane >> 3) & 3);  // swizzled global chunk
    const int segrow  = 32 * wave + (lane >> 2);         // rows 32w .. 32w+15
    const _Float16* gA = E + (size_t)(row0 + segrow) * DIM + c * 8;
    const _Float16* gB = E + (size_t)(col0 + segrow) * DIM + c * 8;
    _Float16* lA = As + (2 * wave) * 512;                // seg 2w base (elements)
    _Float16* lB = Bs + (2 * wave) * 512;

    // ds_read slot for fragments: p = quad ^ ((l16>>1)&3)
    const int p = quad ^ ((l16 >> 1) & 3);

    floatx4 acc[4][4] = {};

    for (int kk = 0; kk < DIM; kk += BK) {
        __syncthreads();                       // prev iter's ds_reads done
        load16_to_lds(gA,            lA);      // rows 32w..32w+15
        load16_to_lds(gA + 16 * DIM, lA + 512);// rows 32w+16..32w+31
        load16_to_lds(gB,            lB);
        load16_to_lds(gB + 16 * DIM, lB + 512);
        gA += BK; gB += BK;
        __syncthreads();                       // drains vmcnt -> LDS visible

        half8 af[4], bf[4];
        #pragma unroll
        for (int mi = 0; mi < 4; ++mi)
            af[mi] = *(const half8*)&As[(wr*64 + mi*16 + l16) * BK + p*8];
        #pragma unroll
        for (int ni = 0; ni < 4; ++ni)
            bf[ni] = *(const half8*)&Bs[(wc*64 + ni*16 + l16) * BK + p*8];

        #pragma unroll
        for (int mi = 0; mi < 4; ++mi)
            #pragma unroll
            for (int ni = 0; ni < 4; ++ni)
                acc[mi][ni] = __builtin_amdgcn_mfma_f32_16x16x32_f16(
                    af[mi], bf[ni], acc[mi][ni], 0, 0, 0);
    }

    // ---- epilogue: loss on the 64x64 wave subtile ----
    // C/D layout: col = lane&15, row = quad*4 + reg  [m89-verified]
    float lsum = 0.0f;
    #pragma unroll
    for (int mi = 0; mi < 4; ++mi) {
        const int tr_base = wr*64 + mi*16 + quad*4;
        #pragma unroll
        for (int ni = 0; ni < 4; ++ni) {
            const int tc = wc*64 + ni*16 + l16;
            const int gj = col0 + tc;
            const int lc = clab[tc];
            #pragma unroll
            for (int reg = 0; reg < 4; ++reg) {
                const int tr = tr_base + reg;
                const int gi = row0 + tr;
                const float s = acc[mi][ni][reg];
                if (gi != gj) {
                    if (rlab[tr] == lc) {
                        const float u = 1.0f - s;
                        lsum += u * u;
                    } else {
                        const float u = s - 0.5f;
                        if (u > 0.0f) lsum += u * u;
                    }
                }
            }
        }
    }

    lsum *= (br == bc) ? 1.0f : 2.0f;   // off-diagonal blocks count twice

    #pragma unroll
    for (int off = 32; off > 0; off >>= 1) lsum += __shfl_down(lsum, off);
    if (lane == 0) wsum[wave] = lsum;
    __syncthreads();
    if (t == 0) {
        const float tot = wsum[0] + wsum[1] + wsum[2] + wsum[3];
        atomicAdd(out, tot * (1.0f / 67100672.0f));  // N*(N-1) = 8192*8191
    }
}

// ---------------- launch ----------------
extern "C" void kernel_launch(void* const* d_in, const int* in_sizes, int n_in,
                              void* d_out, int out_size, void* d_ws, size_t ws_size,
                              hipStream_t stream)
{
    (void)in_sizes; (void)n_in; (void)out_size; (void)ws_size;

    const float* emb    = (const float*)d_in[0];
    const int*   labels = (const int*)d_in[1];
    float*       out    = (float*)d_out;
    _Float16*    En     = (_Float16*)d_ws;   // 8192*512*2 = 8 MB

    normalize_kernel<<<N_ROWS, 128, 0, stream>>>(emb, En, out);

    const int nblocks = NB * (NB + 1) / 2;   // 2080
    gemmloss_kernel<<<nblocks, 256, 0, stream>>>(En, labels, out);
}

// Round 3
// 113.449 us; speedup vs baseline: 1.2137x; 1.1412x over previous
//
#include <hip/hip_runtime.h>
#include <hip/hip_bf16.h>
#include <math.h>

#define N_ROWS 8192
#define DIM    512           // elements per row; fp8 row = 512 B
#define BM     128
#define BKB    64            // K-slab in BYTES per iter (64 fp8 elems) = 4 x 16B chunks
#define NB     (N_ROWS / BM) // 64

typedef float floatx4 __attribute__((ext_vector_type(4)));

// ---------------- async global->LDS, 16B per lane ----------------
__device__ __forceinline__ void load16_to_lds(const void* g, void* l) {
    __builtin_amdgcn_global_load_lds(
        (const __attribute__((address_space(1))) unsigned int*)g,
        (__attribute__((address_space(3))) unsigned int*)l,
        16, 0, 0);
}

// ------------- Kernel 1: L2-normalize fp32 -> fp8 e4m3 (x16), zero d_out ----
// sim recovered as acc * (1/256) in the GEMM epilogue.
__global__ __launch_bounds__(128) void normalize_kernel(
    const float* __restrict__ emb, unsigned char* __restrict__ out,
    float* __restrict__ loss_out)
{
    const int row = blockIdx.x;
    const int t   = threadIdx.x;
    if (row == 0 && t == 0) loss_out[0] = 0.0f;

    const float4* rp = (const float4*)(emb + (size_t)row * DIM);
    float4 v = rp[t];                      // 128 thr * 4 = 512
    float ss = v.x*v.x + v.y*v.y + v.z*v.z + v.w*v.w;

    #pragma unroll
    for (int off = 32; off > 0; off >>= 1) ss += __shfl_down(ss, off);

    __shared__ float sred[2];
    if ((t & 63) == 0) sred[t >> 6] = ss;
    __syncthreads();
    const float tot = sred[0] + sred[1];
    const float rs  = 16.0f / fmaxf(sqrtf(tot), 1e-12f);   // normalize * 16

    int pk = 0;
    pk = __builtin_amdgcn_cvt_pk_fp8_f32(v.x * rs, v.y * rs, pk, false);
    pk = __builtin_amdgcn_cvt_pk_fp8_f32(v.z * rs, v.w * rs, pk, true);
    ((int*)(out + (size_t)row * DIM))[t] = pk;   // bytes x,y,z,w little-endian
}

// ------------- Kernel 2: fused fp8 E*E^T tile + contrastive loss -------------
// LDS tile: 128 rows x 64 B, unpadded. 16B chunk c of row r stored at slot
// p = c ^ ((r>>1)&3) (realized on the GLOBAL address side of the DMA).
// ds_read_b64 fragments then land 2 dwords/bank across the wave (free).
__global__ __launch_bounds__(256) void gemmloss_kernel(
    const unsigned char* __restrict__ E, const int* __restrict__ labels,
    float* __restrict__ out)
{
    __shared__ __align__(16) unsigned char As[BM * BKB];   // 8 KB
    __shared__ __align__(16) unsigned char Bs[BM * BKB];   // 8 KB
    __shared__ int   rlab[BM];
    __shared__ int   clab[BM];
    __shared__ float wsum[4];

    // ---- decode triangular block id (br <= bc) ----
    const int bid = blockIdx.x;
    int br = (int)((2.0f * NB + 1.0f -
                    sqrtf((float)((2*NB+1)*(2*NB+1) - 8*bid))) * 0.5f);
    #define TRI_START(r) ((r)*NB - ((r)*((r)-1))/2)
    while (br > 0 && TRI_START(br) > bid) --br;
    while (TRI_START(br + 1) <= bid) ++br;
    const int bc = br + (bid - TRI_START(br));
    #undef TRI_START

    const int row0 = br * BM;
    const int col0 = bc * BM;

    const int t = threadIdx.x;
    if (t < BM) rlab[t]       = labels[row0 + t];
    else        clab[t - BM]  = labels[col0 + (t - BM)];

    const int wave = t >> 6;
    const int lane = t & 63;
    const int wr   = wave >> 1;   // wave row (0..1)
    const int wc   = wave & 1;    // wave col (0..1)
    const int quad = lane >> 4;   // 0..3
    const int l16  = lane & 15;   // 0..15

    // ---- staging: wave w stages rows [32w, 32w+32), 16 rows per DMA ----
    const int c      = (lane & 3) ^ ((lane >> 3) & 3);   // swizzled global chunk
    const int segrow = 32 * wave + (lane >> 2);
    const unsigned char* gA = E + (size_t)(row0 + segrow) * DIM + c * 16;
    const unsigned char* gB = E + (size_t)(col0 + segrow) * DIM + c * 16;
    unsigned char* lA = As + wave * 2048;
    unsigned char* lB = Bs + wave * 2048;

    // ds_read byte offsets for the two k-steps (s = 0,1):
    // global chunk c0 = s*2 + (quad>>1); slot p = c0 ^ ((l16>>1)&3); +8 if quad odd
    const int xr   = (l16 >> 1) & 3;
    const int off0 = (((quad >> 1) + 0) ^ xr) * 16 + (quad & 1) * 8;
    const int off1 = (((quad >> 1) + 2) ^ xr) * 16 + (quad & 1) * 8;

    floatx4 acc[4][4] = {};

    for (int kk = 0; kk < DIM; kk += BKB) {
        __syncthreads();                        // prev iter's ds_reads done
        load16_to_lds(gA,             lA);      // rows 32w..32w+15
        load16_to_lds(gA + 16 * DIM,  lA + 1024);
        load16_to_lds(gB,             lB);
        load16_to_lds(gB + 16 * DIM,  lB + 1024);
        gA += BKB; gB += BKB;
        __syncthreads();                        // drains vmcnt -> LDS visible

        long a0[4], a1[4], b0[4], b1[4];
        #pragma unroll
        for (int mi = 0; mi < 4; ++mi) {
            const int rbase = (wr*64 + mi*16 + l16) * BKB;
            a0[mi] = *(const long*)&As[rbase + off0];
            a1[mi] = *(const long*)&As[rbase + off1];
        }
        #pragma unroll
        for (int ni = 0; ni < 4; ++ni) {
            const int rbase = (wc*64 + ni*16 + l16) * BKB;
            b0[ni] = *(const long*)&Bs[rbase + off0];
            b1[ni] = *(const long*)&Bs[rbase + off1];
        }

        #pragma unroll
        for (int mi = 0; mi < 4; ++mi)
            #pragma unroll
            for (int ni = 0; ni < 4; ++ni) {
                acc[mi][ni] = __builtin_amdgcn_mfma_f32_16x16x32_fp8_fp8(
                    a0[mi], b0[ni], acc[mi][ni], 0, 0, 0);
                acc[mi][ni] = __builtin_amdgcn_mfma_f32_16x16x32_fp8_fp8(
                    a1[mi], b1[ni], acc[mi][ni], 0, 0, 0);
            }
    }

    // ---- epilogue: loss on the 64x64 wave subtile ----
    // C/D layout: col = lane&15, row = quad*4 + reg  [m89; dtype-independent]
    float lsum = 0.0f;
    #pragma unroll
    for (int mi = 0; mi < 4; ++mi) {
        const int tr_base = wr*64 + mi*16 + quad*4;
        #pragma unroll
        for (int ni = 0; ni < 4; ++ni) {
            const int tc = wc*64 + ni*16 + l16;
            const int gj = col0 + tc;
            const int lc = clab[tc];
            #pragma unroll
            for (int reg = 0; reg < 4; ++reg) {
                const int tr = tr_base + reg;
                const int gi = row0 + tr;
                const float s = acc[mi][ni][reg] * (1.0f / 256.0f);  // undo 16x16
                if (gi != gj) {
                    if (rlab[tr] == lc) {
                        const float u = 1.0f - s;
                        lsum += u * u;
                    } else {
                        const float u = s - 0.5f;
                        if (u > 0.0f) lsum += u * u;
                    }
                }
            }
        }
    }

    lsum *= (br == bc) ? 1.0f : 2.0f;   // off-diagonal blocks count twice

    #pragma unroll
    for (int off = 32; off > 0; off >>= 1) lsum += __shfl_down(lsum, off);
    if (lane == 0) wsum[wave] = lsum;
    __syncthreads();
    if (t == 0) {
        const float tot = wsum[0] + wsum[1] + wsum[2] + wsum[3];
        atomicAdd(out, tot * (1.0f / 67100672.0f));  // N*(N-1)
    }
}

// ---------------- launch ----------------
extern "C" void kernel_launch(void* const* d_in, const int* in_sizes, int n_in,
                              void* d_out, int out_size, void* d_ws, size_t ws_size,
                              hipStream_t stream)
{
    (void)in_sizes; (void)n_in; (void)out_size; (void)ws_size;

    const float* emb    = (const float*)d_in[0];
    const int*   labels = (const int*)d_in[1];
    float*       out    = (float*)d_out;
    unsigned char* E8   = (unsigned char*)d_ws;   // 8192*512 = 4 MB fp8

    normalize_kernel<<<N_ROWS, 128, 0, stream>>>(emb, E8, out);

    const int nblocks = NB * (NB + 1) / 2;   // 2080
    gemmloss_kernel<<<nblocks, 256, 0, stream>>>(E8, labels, out);
}